// Round 8
// baseline (918.011 us; speedup 1.0000x reference)
//
#include <hip/hip_runtime.h>

#define NTOK 262144   // 64*64*64 tokens per batch
#define NCH  64
#define NB   4

#define BTOK 256      // tokens per block per iteration (4 waves x 64)
#define NIT  4        // iterations per block
#define GRIDX (NTOK / (BTOK * NIT))   // 256 blocks per batch

// ws layout (floats): S[4][4] @0, m[4][4][64] @16, rc[4][64] @1040
#define WS_S  0
#define WS_M  16
#define WS_RC 1040

typedef float floatx4 __attribute__((ext_vector_type(4)));   // native vec for nontemporal

// Fused keys+msum: x read from HBM exactly once.
// Lane layout: q = l>>4 owns channels [16q,16q+16); lh = l&15 owns tokens
// lh*4..+3 of the wave's 64-token tile. Tile xr[16] (64 VGPR) + macc[64]
// (64 VGPR) both statically indexed; __launch_bounds__(256,1) prevents the
// r5 spill (VGPR cap 512).
__global__ __launch_bounds__(256, 1)
void ea3d_fused(const float* __restrict__ x, const float* __restrict__ Wk,
                float* __restrict__ ws)
{
    __shared__ __align__(16) float wk4[NCH * 4];   // wk4[c][h]
    __shared__ float ssum[4][4];

    const int tid = threadIdx.x;
    const int w   = tid >> 6;
    const int l   = tid & 63;
    const int b   = blockIdx.y;

    { int c = tid >> 2, h = tid & 3; wk4[(c << 2) + h] = Wk[h * NCH + c]; }
    __syncthreads();

    const int q  = l >> 4;
    const int lh = l & 15;
    const int c0 = q << 4;
    const float* xb = x + ((size_t)b * NCH + c0) * NTOK;

    float macc[64];                    // macc[i*4+h], channel c0+i — static only
    #pragma unroll
    for (int r = 0; r < 64; ++r) macc[r] = 0.f;
    float sacc[4] = {0.f, 0.f, 0.f, 0.f};

    for (int it = 0; it < NIT; ++it) {
        const size_t n0 = ((size_t)blockIdx.x * NIT + it) * BTOK + (w << 6) + (lh << 2);

        // ---- single global read of this tile slice: 16 channel rows x 4 tokens ----
        float4 xr[16];
        #pragma unroll
        for (int i = 0; i < 16; ++i)
            xr[i] = *(const float4*)(xb + (size_t)i * NTOK + n0);

        // ---- keys partial over this lane's 16 channels ----
        float k[16];   // k[h*4 + j]
        #pragma unroll
        for (int r = 0; r < 16; ++r) k[r] = 0.f;
        #pragma unroll
        for (int i = 0; i < 16; ++i) {
            float4 wv = *((const float4*)wk4 + (c0 + i));
            float4 xv = xr[i];
            k[0]  += wv.x * xv.x; k[1]  += wv.x * xv.y; k[2]  += wv.x * xv.z; k[3]  += wv.x * xv.w;
            k[4]  += wv.y * xv.x; k[5]  += wv.y * xv.y; k[6]  += wv.y * xv.z; k[7]  += wv.y * xv.w;
            k[8]  += wv.z * xv.x; k[9]  += wv.z * xv.y; k[10] += wv.z * xv.z; k[11] += wv.z * xv.w;
            k[12] += wv.w * xv.x; k[13] += wv.w * xv.y; k[14] += wv.w * xv.z; k[15] += wv.w * xv.w;
        }
        // combine the 4 channel quarters: lanes {l, l^16, l^32, l^48}
        #pragma unroll
        for (int r = 0; r < 16; ++r) {
            k[r] += __shfl_xor(k[r], 16);
            k[r] += __shfl_xor(k[r], 32);
        }

        // ---- e = exp(k); S partial (each token counted 4x -> scale later) ----
        float e[16];
        #pragma unroll
        for (int r = 0; r < 16; ++r) e[r] = __expf(k[r]);
        #pragma unroll
        for (int h = 0; h < 4; ++h)
            sacc[h] += (e[h*4+0] + e[h*4+1]) + (e[h*4+2] + e[h*4+3]);

        // ---- m accumulation, all in registers, all static ----
        #pragma unroll
        for (int i = 0; i < 16; ++i) {
            float4 xv = xr[i];
            macc[i*4+0] += e[0] *xv.x + e[1] *xv.y + e[2] *xv.z + e[3] *xv.w;
            macc[i*4+1] += e[4] *xv.x + e[5] *xv.y + e[6] *xv.z + e[7] *xv.w;
            macc[i*4+2] += e[8] *xv.x + e[9] *xv.y + e[10]*xv.z + e[11]*xv.w;
            macc[i*4+3] += e[12]*xv.x + e[13]*xv.y + e[14]*xv.z + e[15]*xv.w;
        }
    }

    // ---- final: reduce macc across the 16 token-lanes (same q) ----
    #pragma unroll
    for (int r = 0; r < 64; ++r) {
        float v = macc[r];
        v += __shfl_xor(v, 1);
        v += __shfl_xor(v, 2);
        v += __shfl_xor(v, 4);
        v += __shfl_xor(v, 8);
        macc[r] = v;
    }
    if (lh == 0) {     // lanes 0,16,32,48: disjoint channel quarters
        float* mb = ws + WS_M + (size_t)(b * 4) * NCH + c0;
        #pragma unroll
        for (int i = 0; i < 16; ++i) {
            #pragma unroll
            for (int h = 0; h < 4; ++h)
                __hip_atomic_fetch_add(mb + h * NCH + i, macc[i*4+h],
                                       __ATOMIC_RELAXED, __HIP_MEMORY_SCOPE_AGENT);
        }
    }

    // ---- S: reduce over 64 lanes (4x duplication -> 0.25), block, then global ----
    #pragma unroll
    for (int h = 0; h < 4; ++h) {
        float v = sacc[h];
        #pragma unroll
        for (int off = 32; off; off >>= 1) v += __shfl_xor(v, off);
        sacc[h] = 0.25f * v;
    }
    if (l == 0) {
        #pragma unroll
        for (int h = 0; h < 4; ++h) ssum[w][h] = sacc[h];
    }
    __syncthreads();
    if (tid < 4) {
        float s = (ssum[0][tid] + ssum[1][tid]) + (ssum[2][tid] + ssum[3][tid]);
        __hip_atomic_fetch_add(ws + WS_S + b * 4 + tid, s,
                               __ATOMIC_RELAXED, __HIP_MEMORY_SCOPE_AGENT);
    }
}

// ---------- finalize: context = Wv*(m/S)+bv ; rc = Wr*context + br ----------
__global__ void ea3d_finalize(const float* __restrict__ Wv, const float* __restrict__ bv,
                              const float* __restrict__ Wr, const float* __restrict__ br,
                              float* __restrict__ ws)
{
    __shared__ float ctx[NB * 32];
    const int tid = threadIdx.x;
    if (tid < 128) {
        int b = tid >> 5, hv = tid & 31, h = hv >> 3;
        float inv = 1.0f / ws[WS_S + b * 4 + h];
        const float* m = ws + WS_M + (b * 4 + h) * NCH;
        const float* wvr = Wv + hv * NCH;
        float acc = 0.f;
        #pragma unroll
        for (int c = 0; c < NCH; ++c) acc += wvr[c] * m[c];
        ctx[b * 32 + hv] = acc * inv + bv[hv];
    }
    __syncthreads();
    int b = tid >> 6, c = tid & 63;
    const float* wrr = Wr + c * 32;
    const float* cb  = ctx + b * 32;
    float acc = br[c];
    #pragma unroll
    for (int hv = 0; hv < 32; ++hv) acc += wrr[hv] * cb[hv];
    ws[WS_RC + b * NCH + c] = acc;
}

// ---------- out = x + rc[b][c]  (nontemporal stores: don't evict x) ----------
__global__ __launch_bounds__(256)
void ea3d_add(const float* __restrict__ x, const float* __restrict__ ws,
              float* __restrict__ out)
{
    const int row = blockIdx.y;                 // b*64 + c
    const float rc = ws[WS_RC + row];
    const size_t base = (size_t)row * NTOK;
    const float4*  xp = (const float4*)(x + base);
    floatx4*       op = (floatx4*)(out + base);
    const int nvec = NTOK / 4;
    for (int i = blockIdx.x * blockDim.x + threadIdx.x; i < nvec;
         i += gridDim.x * blockDim.x) {
        float4 v = xp[i];
        floatx4 nv = { v.x + rc, v.y + rc, v.z + rc, v.w + rc };
        __builtin_nontemporal_store(nv, op + i);
    }
}

extern "C" void kernel_launch(void* const* d_in, const int* in_sizes, int n_in,
                              void* d_out, int out_size, void* d_ws, size_t ws_size,
                              hipStream_t stream)
{
    const float* x  = (const float*)d_in[0];
    const float* Wk = (const float*)d_in[1];
    // d_in[2]=bk (cancels in token-softmax); d_in[3]=Wq, d_in[4]=bq (softmax over
    // size-1 head-channel axis -> identically 1.0, so Wq/bq are dead)
    const float* Wv = (const float*)d_in[5];
    const float* bv = (const float*)d_in[6];
    const float* Wr = (const float*)d_in[7];
    const float* br = (const float*)d_in[8];
    float* out = (float*)d_out;
    float* ws  = (float*)d_ws;

    (void)hipMemsetAsync(ws, 0, WS_RC * sizeof(float), stream);  // zero S + m accumulators
    ea3d_fused<<<dim3(GRIDX, NB), 256, 0, stream>>>(x, Wk, ws);
    ea3d_finalize<<<1, 256, 0, stream>>>(Wv, bv, Wr, br, ws);
    ea3d_add<<<dim3(32, NB * NCH), 256, 0, stream>>>(x, ws, out);
}